// Round 12
// baseline (158.735 us; speedup 1.0000x reference)
//
#include <hip/hip_runtime.h>
#include <hip/hip_bf16.h>
#include <stdint.h>

typedef __attribute__((ext_vector_type(8))) short short8;
typedef __attribute__((ext_vector_type(4))) float f32x4;
typedef __attribute__((ext_vector_type(16))) float f32x16;
typedef _Float16 f16x8 __attribute__((ext_vector_type(8)));
typedef unsigned int u32x4 __attribute__((ext_vector_type(4)));
typedef unsigned short u16x4 __attribute__((ext_vector_type(4)));

#define QMAXF 255.0f
#define MFMA_F16(a, b, c) __builtin_amdgcn_mfma_f32_32x32x16_f16(a, b, c, 0, 0, 0)

constexpr int Bb = 4, Ss = 1024, Ee = 1024, Hh = 16, Dd = 64;
constexpr int Mm = Bb * Ss;   // 4096
constexpr int F3 = 3 * Ee;    // 3072
constexpr int Kk = Ee;        // 1024

__device__ __forceinline__ unsigned short f2bf_exact(float f) {
    return (unsigned short)(__float_as_uint(f) >> 16);
}

// pack hi/lo f16 split of v into one u32: (lo16 << 16) | hi16   (RTE casts)
__device__ __forceinline__ unsigned pack_hl(float v) {
    _Float16 h = (_Float16)v;
    _Float16 l = (_Float16)(v - (float)h);
    return ((unsigned)__builtin_bit_cast(unsigned short, l) << 16) |
           (unsigned)__builtin_bit_cast(unsigned short, h);
}

// fused fake-quant of x, W_qkv, W_proj -> integer-valued bf16 (f32x4 vectorized)
__global__ void quant_all(const float* __restrict__ x,
                          const float* __restrict__ Wq,
                          const float* __restrict__ Wp,
                          const float* __restrict__ s_act, const float* __restrict__ zp_act,
                          const float* __restrict__ swq, const float* __restrict__ zwq,
                          const float* __restrict__ swp, const float* __restrict__ zwp,
                          unsigned short* __restrict__ xq,
                          unsigned short* __restrict__ wqq,
                          unsigned short* __restrict__ wpq) {
    constexpr int NX = Mm * Ee / 4;
    constexpr int NWQ = F3 * Ee / 4;
    constexpr int NWP = Ee * Ee / 4;
    const float sa = s_act[0], za = zp_act[0];
    for (int i = blockIdx.x * blockDim.x + threadIdx.x; i < NX + NWQ + NWP;
         i += gridDim.x * blockDim.x) {
        const float* src;
        unsigned short* dst;
        float s, zp;
        if (i < NX) {
            src = x + i * 4; dst = xq + i * 4; s = sa; zp = za;
        } else if (i < NX + NWQ) {
            int j = i - NX;
            int r = (j * 4) >> 10;
            src = Wq + j * 4; dst = wqq + j * 4; s = swq[r]; zp = zwq[r];
        } else {
            int j = i - NX - NWQ;
            int r = (j * 4) >> 10;
            src = Wp + j * 4; dst = wpq + j * 4; s = swp[r]; zp = zwp[r];
        }
        f32x4 v = *(const f32x4*)src;
        u16x4 o;
        #pragma unroll
        for (int e = 0; e < 4; ++e) {
            float q = v[e] / s + zp;
            q = fminf(fmaxf(q, 0.0f), QMAXF);
            o[e] = f2bf_exact(rintf(q) - zp);
        }
        *(u16x4*)dst = o;
    }
}

// bf16 integer MFMA GEMM (frozen numerics). BK=64: 16 K-steps, two 32-wide
// MFMA sub-steps per barrier pair (same MFMA order as BK=32 -> bit-identical).
// MODE 0: q,k -> packed-hl u32 planes [BH][S][D]; v -> packed V^T [BH][D][S]
// MODE 1: fp32 [M][1024] to o0 (NT)
template<int MODE>
__global__ __launch_bounds__(256)
void gemm_fq(const unsigned short* __restrict__ A,
             const unsigned short* __restrict__ Bw,
             const float* __restrict__ sa_p,
             const float* __restrict__ sw_v,
             const float* __restrict__ bias_v,
             float* __restrict__ o0,
             unsigned* __restrict__ pq, unsigned* __restrict__ pk, unsigned* __restrict__ pv,
             int ntiles) {
    __shared__ unsigned short At[128][64];   // 16KB
    __shared__ unsigned short Bt[128][64];   // 16KB
    const int t = threadIdx.x;
    const int nwg = gridDim.x;
    const int swz = (blockIdx.x & 7) * (nwg >> 3) + (blockIdx.x >> 3);
    const int tile_m = (swz / ntiles) * 128;
    const int tile_n = (swz % ntiles) * 128;
    const int lane = t & 63, wid = t >> 6;
    const int wr = wid >> 1, wc = wid & 1;
    const int srow = t >> 1, scol = (t & 1) * 32;
    const float sa = sa_p[0];

    const unsigned short* ga = A + (size_t)(tile_m + srow) * Kk + scol;
    const unsigned short* gb = Bw + (size_t)(tile_n + srow) * Kk + scol;

    f32x4 acc[4][4];
    #pragma unroll
    for (int i = 0; i < 4; ++i)
        #pragma unroll
        for (int j = 0; j < 4; ++j)
            #pragma unroll
            for (int e = 0; e < 4; ++e) acc[i][j][e] = 0.0f;

    short8 ra[4], rb[4];
    #pragma unroll
    for (int i = 0; i < 4; ++i) {
        ra[i] = *(const short8*)(ga + i * 8);
        rb[i] = *(const short8*)(gb + i * 8);
    }

    const int NKT = Kk / 64;                 // 16
    for (int kt = 0; kt < NKT; ++kt) {
        __syncthreads();
        #pragma unroll
        for (int i = 0; i < 4; ++i) {
            *(short8*)&At[srow][scol + i * 8] = ra[i];
            *(short8*)&Bt[srow][scol + i * 8] = rb[i];
        }
        __syncthreads();
        // prefetch next K-slab into registers while MFMAs run
        int kn = (kt + 1 < NKT) ? (kt + 1) * 64 : kt * 64;
        #pragma unroll
        for (int i = 0; i < 4; ++i) {
            ra[i] = *(const short8*)(ga + kn + i * 8);
            rb[i] = *(const short8*)(gb + kn + i * 8);
        }

        const int rowA = wr * 64 + (lane & 15);
        const int rowB = wc * 64 + (lane & 15);
        #pragma unroll
        for (int kk = 0; kk < 2; ++kk) {     // same k order as BK=32 pairs
            const int kq = kk * 32 + (lane >> 4) * 8;
            short8 af[4], bfr[4];
            #pragma unroll
            for (int i = 0; i < 4; ++i) af[i] = *(const short8*)&At[rowA + i * 16][kq];
            #pragma unroll
            for (int j = 0; j < 4; ++j) bfr[j] = *(const short8*)&Bt[rowB + j * 16][kq];
            __builtin_amdgcn_s_setprio(1);
            #pragma unroll
            for (int i = 0; i < 4; ++i)
                #pragma unroll
                for (int j = 0; j < 4; ++j)
                    acc[i][j] = __builtin_amdgcn_mfma_f32_16x16x32_bf16(af[i], bfr[j], acc[i][j], 0, 0, 0);
            __builtin_amdgcn_s_setprio(0);
        }
    }

    // C/D layout: col = lane&15, row = (lane>>4)*4 + reg
    const int lr4 = (lane >> 4) * 4;
    const int lc = lane & 15;
    #pragma unroll
    for (int j = 0; j < 4; ++j) {
        int n = tile_n + wc * 64 + j * 16 + lc;
        float sw = sw_v[n] * sa;
        float bv = bias_v[n];
        #pragma unroll
        for (int i = 0; i < 4; ++i) {
            int mbase = tile_m + wr * 64 + i * 16 + lr4;
            float vals[4];
            #pragma unroll
            for (int r = 0; r < 4; ++r) vals[r] = acc[i][j][r] * sw + bv;
            if (MODE == 0) {
                int which = n >> 10, hh = (n >> 6) & 15, d = n & 63;
                int bi = mbase >> 10, si0 = mbase & 1023;
                if (which == 2) {
                    u32x4 pv4;
                    #pragma unroll
                    for (int r = 0; r < 4; ++r) pv4[r] = pack_hl(vals[r]);
                    *(u32x4*)(pv + (((size_t)(bi * Hh + hh)) * Dd + d) * Ss + si0) = pv4;
                } else {
                    unsigned* dst = (which == 0) ? pq : pk;
                    #pragma unroll
                    for (int r = 0; r < 4; ++r)
                        dst[(((size_t)(bi * Hh + hh)) * Ss + si0 + r) * Dd + d] = pack_hl(vals[r]);
                }
            } else {
                #pragma unroll
                for (int r = 0; r < 4; ++r)
                    __builtin_nontemporal_store(vals[r], &o0[(size_t)(mbase + r) * Ee + n]);
            }
        }
    }
}

// Fused flash attention: packed-hl u32 inputs; v_perm unpack in staging
// reconstructs the SAME f16 hi/lo LDS image (bit-exact). XCD-grouped mapping.
__global__ __launch_bounds__(256, 2)
void attn_mfma(const unsigned* __restrict__ pq, const unsigned* __restrict__ pk,
               const unsigned* __restrict__ pv,
               const float* __restrict__ s_at_p, const float* __restrict__ zp_at_p,
               const float* __restrict__ s_ap_p, const float* __restrict__ zp_ap_p,
               unsigned short* __restrict__ outq) {
    __shared__ uint4 lds4[65536 / 16];   // 2 x 32KB double buffer
    char* lds = (char*)lds4;

    const int t = threadIdx.x;
    const int lane = t & 63;
    const int w = t >> 6;
    const int l31 = lane & 31;
    const int lhalf = lane >> 5;
    // XCD-grouped: xcd g&7 owns bh in [xcd*8, xcd*8+8); qt varies fastest
    const int g = blockIdx.x;
    const int ord = g >> 3;
    const int bh = (g & 7) * 8 + (ord >> 3);
    const int qt = ord & 7;
    const int b = bh >> 4, h = bh & 15;

    const float s_at = s_at_p[0], zp_at = zp_at_p[0];
    const float zp_ap = zp_ap_p[0];
    const float c1 = 0.125f / s_at;
    const float c2 = s_at * 1.44269504088896f;
    const float inv_sap = 1.0f / s_ap_p[0];

    #define UNPK_H(bx, ax) __builtin_amdgcn_perm((bx), (ax), 0x05040100u)
    #define UNPK_L(bx, ax) __builtin_amdgcn_perm((bx), (ax), 0x07060302u)

    // Q: load packed, unpack once
    const int qrow = qt * 128 + w * 32 + l31;
    const size_t qbase = ((size_t)bh * Ss + qrow) * Dd;
    f16x8 Qh[4], Ql[4];
    #pragma unroll
    for (int ks = 0; ks < 4; ++ks) {
        int dd = ks * 16 + lhalf * 8;
        u32x4 qa = *(const u32x4*)(pq + qbase + dd);
        u32x4 qb = *(const u32x4*)(pq + qbase + dd + 4);
        u32x4 hw, lw;
        hw[0] = UNPK_H(qa[1], qa[0]); lw[0] = UNPK_L(qa[1], qa[0]);
        hw[1] = UNPK_H(qa[3], qa[2]); lw[1] = UNPK_L(qa[3], qa[2]);
        hw[2] = UNPK_H(qb[1], qb[0]); lw[2] = UNPK_L(qb[1], qb[0]);
        hw[3] = UNPK_H(qb[3], qb[2]); lw[3] = UNPK_L(qb[3], qb[2]);
        Qh[ks] = __builtin_bit_cast(f16x8, hw);
        Ql[ks] = __builtin_bit_cast(f16x8, lw);
    }

    f32x16 o0, o1;
    #pragma unroll
    for (int i = 0; i < 16; ++i) { o0[i] = 0.0f; o1[i] = 0.0f; }
    float m_run = -1e30f, l_run = 0.0f;

    const int srow = t >> 2;              // 0..63
    const int sch = (t & 3) * 2;          // 0,2,4,6
    const int swz0 = ((sch    ) ^ (srow & 7)) << 4;
    const int swz1 = ((sch + 1) ^ (srow & 7)) << 4;
    const int rb = srow * 128;
    const size_t kgrow = ((size_t)bh * Ss + srow) * Dd + sch * 8;   // u32 elems
    const size_t vgrow = ((size_t)bh * Dd + srow) * Ss + sch * 8;

    u32x4 sk[4], sv[4];
    #define STAGE_LOAD(tl) {                                            \
        const size_t ko = kgrow + (size_t)(tl) * 64 * 64;               \
        const size_t vo = vgrow + (size_t)(tl) * 64;                    \
        sk[0] = *(const u32x4*)(pk + ko);                               \
        sk[1] = *(const u32x4*)(pk + ko + 4);                           \
        sk[2] = *(const u32x4*)(pk + ko + 8);                           \
        sk[3] = *(const u32x4*)(pk + ko + 12);                          \
        sv[0] = *(const u32x4*)(pv + vo);                               \
        sv[1] = *(const u32x4*)(pv + vo + 4);                           \
        sv[2] = *(const u32x4*)(pv + vo + 8);                           \
        sv[3] = *(const u32x4*)(pv + vo + 12);                          \
    }
    #define STAGE_WRITE(bsel) {                                         \
        u32x4 kh0, kl0, kh1, kl1, vh0, vl0, vh1, vl1;                   \
        _Pragma("unroll")                                               \
        for (int w2 = 0; w2 < 4; ++w2) {                                \
            unsigned a0 = sk[w2 >> 1][(w2 & 1) * 2];                    \
            unsigned b0 = sk[w2 >> 1][(w2 & 1) * 2 + 1];                \
            kh0[w2] = UNPK_H(b0, a0); kl0[w2] = UNPK_L(b0, a0);         \
            unsigned a1 = sk[2 + (w2 >> 1)][(w2 & 1) * 2];              \
            unsigned b1 = sk[2 + (w2 >> 1)][(w2 & 1) * 2 + 1];          \
            kh1[w2] = UNPK_H(b1, a1); kl1[w2] = UNPK_L(b1, a1);         \
            unsigned c0 = sv[w2 >> 1][(w2 & 1) * 2];                    \
            unsigned d0 = sv[w2 >> 1][(w2 & 1) * 2 + 1];                \
            vh0[w2] = UNPK_H(d0, c0); vl0[w2] = UNPK_L(d0, c0);         \
            unsigned c1x = sv[2 + (w2 >> 1)][(w2 & 1) * 2];             \
            unsigned d1 = sv[2 + (w2 >> 1)][(w2 & 1) * 2 + 1];          \
            vh1[w2] = UNPK_H(d1, c1x); vl1[w2] = UNPK_L(d1, c1x);       \
        }                                                               \
        char* base = lds + (bsel) * 32768;                              \
        *(u32x4*)(base +     0 + rb + swz0) = kh0;                      \
        *(u32x4*)(base +     0 + rb + swz1) = kh1;                      \
        *(u32x4*)(base +  8192 + rb + swz0) = kl0;                      \
        *(u32x4*)(base +  8192 + rb + swz1) = kl1;                      \
        *(u32x4*)(base + 16384 + rb + swz0) = vh0;                      \
        *(u32x4*)(base + 16384 + rb + swz1) = vh1;                      \
        *(u32x4*)(base + 24576 + rb + swz0) = vl0;                      \
        *(u32x4*)(base + 24576 + rb + swz1) = vl1;                      \
    }

    STAGE_LOAD(0);
    STAGE_WRITE(0);
    __syncthreads();

    for (int tile = 0; tile < 16; ++tile) {
        const int bsel = tile & 1;
        char* B = lds + bsel * 32768;
        if (tile < 15) STAGE_LOAD(tile + 1);

        // ---- S^T = K * Q^T (3 split products) ----
        f32x16 s0, s1;
        #pragma unroll
        for (int i = 0; i < 16; ++i) { s0[i] = 0.0f; s1[i] = 0.0f; }
        __builtin_amdgcn_s_setprio(1);
        #pragma unroll
        for (int ks = 0; ks < 4; ++ks) {
            const int dchunk = ks * 2 + lhalf;
            {
                const int kr = l31;
                const char* a = B + kr * 128 + ((dchunk ^ (kr & 7)) << 4);
                f16x8 ah = *(const f16x8*)(a);
                f16x8 al = *(const f16x8*)(a + 8192);
                s0 = MFMA_F16(ah, Qh[ks], s0);
                s0 = MFMA_F16(ah, Ql[ks], s0);
                s0 = MFMA_F16(al, Qh[ks], s0);
            }
            {
                const int kr = 32 + l31;
                const char* a = B + kr * 128 + ((dchunk ^ (kr & 7)) << 4);
                f16x8 ah = *(const f16x8*)(a);
                f16x8 al = *(const f16x8*)(a + 8192);
                s1 = MFMA_F16(ah, Qh[ks], s1);
                s1 = MFMA_F16(ah, Ql[ks], s1);
                s1 = MFMA_F16(al, Qh[ks], s1);
            }
        }
        __builtin_amdgcn_s_setprio(0);

        // ---- integer-domain fake-quant + online softmax ----
        float rq[32];
        #pragma unroll
        for (int r = 0; r < 16; ++r) {
            float q0 = fmaf(s0[r], c1, zp_at);
            q0 = fminf(fmaxf(q0, 0.0f), QMAXF);
            rq[r] = rintf(q0);
            float q1 = fmaf(s1[r], c1, zp_at);
            q1 = fminf(fmaxf(q1, 0.0f), QMAXF);
            rq[16 + r] = rintf(q1);
        }
        float mx[16];
        #pragma unroll
        for (int i = 0; i < 16; ++i) mx[i] = fmaxf(rq[2 * i], rq[2 * i + 1]);
        #pragma unroll
        for (int i = 0; i < 8; ++i) mx[i] = fmaxf(mx[i], mx[i + 8]);
        #pragma unroll
        for (int i = 0; i < 4; ++i) mx[i] = fmaxf(mx[i], mx[i + 4]);
        float mloc = fmaxf(fmaxf(mx[0], mx[1]), fmaxf(mx[2], mx[3]));
        mloc = fmaxf(mloc, __shfl_xor(mloc, 32));

        if (!__all(mloc - m_run <= 64.0f)) {   // defer-max: rare rescale
            float mnew = fmaxf(m_run, mloc);
            float fac = exp2f((m_run - mnew) * c2);
            l_run *= fac;
            #pragma unroll
            for (int r = 0; r < 16; ++r) {
                int qr = (r & 3) + 8 * (r >> 2) + 4 * lhalf;
                float f = __shfl(fac, qr);
                o0[r] *= f; o1[r] *= f;
            }
            m_run = mnew;
        }

        float p[32];
        float psum = 0.0f;
        #pragma unroll
        for (int i = 0; i < 32; ++i) {
            p[i] = exp2f((rq[i] - m_run) * c2);
            psum += p[i];
        }
        psum += __shfl_xor(psum, 32);
        l_run += psum;

        // ---- pack P hi/lo + permlane32_swap into A-fragments ----
        unsigned int wH[16], wL[16];
        #pragma unroll
        for (int wi = 0; wi < 16; ++wi) {
            float a = p[2 * wi], bb2 = p[2 * wi + 1];
            auto hh2 = __builtin_amdgcn_cvt_pkrtz(a, bb2);
            wH[wi] = __builtin_bit_cast(unsigned int, hh2);
            float ha = (float)hh2[0], hb = (float)hh2[1];
            auto ll2 = __builtin_amdgcn_cvt_pkrtz(a - ha, bb2 - hb);
            wL[wi] = __builtin_bit_cast(unsigned int, ll2);
        }
        f16x8 fragH[4], fragL[4];
        #pragma unroll
        for (int ks = 0; ks < 4; ++ks) {
            auto h0 = __builtin_amdgcn_permlane32_swap(wH[4 * ks], wH[4 * ks + 2], false, false);
            auto h1 = __builtin_amdgcn_permlane32_swap(wH[4 * ks + 1], wH[4 * ks + 3], false, false);
            fragH[ks] = __builtin_bit_cast(f16x8, (u32x4){h0[0], h1[0], h0[1], h1[1]});
            auto g0 = __builtin_amdgcn_permlane32_swap(wL[4 * ks], wL[4 * ks + 2], false, false);
            auto g1 = __builtin_amdgcn_permlane32_swap(wL[4 * ks + 1], wL[4 * ks + 3], false, false);
            fragL[ks] = __builtin_bit_cast(f16x8, (u32x4){g0[0], g1[0], g0[1], g1[1]});
        }

        // ---- O += P * V (3 split products) ----
        __builtin_amdgcn_s_setprio(1);
        #pragma unroll
        for (int ks = 0; ks < 4; ++ks) {
            const int kch = ks * 2 + lhalf;
            {
                const int dd = l31;
                const char* va = B + 16384 + dd * 128 + ((kch ^ (dd & 7)) << 4);
                f16x8 vh = *(const f16x8*)(va);
                f16x8 vl = *(const f16x8*)(va + 8192);
                o0 = MFMA_F16(fragH[ks], vh, o0);
                o0 = MFMA_F16(fragH[ks], vl, o0);
                o0 = MFMA_F16(fragL[ks], vh, o0);
            }
            {
                const int dd = 32 + l31;
                const char* va = B + 16384 + dd * 128 + ((kch ^ (dd & 7)) << 4);
                f16x8 vh = *(const f16x8*)(va);
                f16x8 vl = *(const f16x8*)(va + 8192);
                o1 = MFMA_F16(fragH[ks], vh, o1);
                o1 = MFMA_F16(fragH[ks], vl, o1);
                o1 = MFMA_F16(fragL[ks], vh, o1);
            }
        }
        __builtin_amdgcn_s_setprio(0);

        if (tile < 15) STAGE_WRITE(bsel ^ 1);
        __syncthreads();
    }

    // ---- epilogue: /l, proj-activation fake-quant, write bf16-int (NT) ----
    float inv = 1.0f / l_run;
    #pragma unroll
    for (int r = 0; r < 16; ++r) {
        int qr = (r & 3) + 8 * (r >> 2) + 4 * lhalf;
        float fis = __shfl(inv, qr) * inv_sap;
        int tok = qt * 128 + w * 32 + qr;
        size_t rowbase = ((size_t)b * Ss + tok) * Ee + h * Dd;
        {
            float qv = fmaf(o0[r], fis, zp_ap);
            qv = fminf(fmaxf(qv, 0.0f), QMAXF);
            __builtin_nontemporal_store(f2bf_exact(rintf(qv) - zp_ap), &outq[rowbase + l31]);
        }
        {
            float qv = fmaf(o1[r], fis, zp_ap);
            qv = fminf(fmaxf(qv, 0.0f), QMAXF);
            __builtin_nontemporal_store(f2bf_exact(rintf(qv) - zp_ap), &outq[rowbase + 32 + l31]);
        }
    }
}

extern "C" void kernel_launch(void* const* d_in, const int* in_sizes, int n_in,
                              void* d_out, int out_size, void* d_ws, size_t ws_size,
                              hipStream_t stream) {
    const float* x           = (const float*)d_in[0];
    const float* W_qkv       = (const float*)d_in[1];
    const float* b_qkv       = (const float*)d_in[2];
    const float* W_proj      = (const float*)d_in[3];
    const float* b_proj      = (const float*)d_in[4];
    const float* s_act_qkv   = (const float*)d_in[5];
    const float* zp_act_qkv  = (const float*)d_in[6];
    const float* s_w_qkv     = (const float*)d_in[7];
    const float* zp_w_qkv    = (const float*)d_in[8];
    const float* s_attn      = (const float*)d_in[9];
    const float* zp_attn     = (const float*)d_in[10];
    const float* s_act_proj  = (const float*)d_in[11];
    const float* zp_act_proj = (const float*)d_in[12];
    const float* s_w_proj    = (const float*)d_in[13];
    const float* zp_w_proj   = (const float*)d_in[14];

    // ws layout (64MB): 0 xq/outq(8) | 8 wqq(6) | 14 wpq(2) | 16 pq(16) | 32 pk(16) | 48 pv(16)
    char* ws = (char*)d_ws;
    unsigned short* xq   = (unsigned short*)(ws);
    unsigned short* outq = (unsigned short*)(ws);
    unsigned short* wqq  = (unsigned short*)(ws + ((size_t)8 << 20));
    unsigned short* wpq  = (unsigned short*)(ws + ((size_t)14 << 20));
    unsigned* pq         = (unsigned*)(ws + ((size_t)16 << 20));
    unsigned* pk         = (unsigned*)(ws + ((size_t)32 << 20));
    unsigned* pv         = (unsigned*)(ws + ((size_t)48 << 20));

    quant_all<<<2048, 256, 0, stream>>>(x, W_qkv, W_proj,
                                        s_act_qkv, zp_act_qkv, s_w_qkv, zp_w_qkv,
                                        s_w_proj, zp_w_proj, xq, wqq, wpq);
    gemm_fq<0><<<768, 256, 0, stream>>>(xq, wqq, s_act_qkv, s_w_qkv, b_qkv,
                                        nullptr, pq, pk, pv, 24);
    attn_mfma<<<512, 256, 0, stream>>>(pq, pk, pv,
                                       s_attn, zp_attn, s_act_proj, zp_act_proj, outq);
    gemm_fq<1><<<256, 256, 0, stream>>>(outq, wpq, s_act_proj, s_w_proj, b_proj,
                                        (float*)d_out, nullptr, nullptr, nullptr, 8);
}

// Round 13
// 154.155 us; speedup vs baseline: 1.0297x; 1.0297x over previous
//
#include <hip/hip_runtime.h>
#include <hip/hip_bf16.h>
#include <stdint.h>

typedef __attribute__((ext_vector_type(8))) short short8;
typedef __attribute__((ext_vector_type(4))) float f32x4;
typedef __attribute__((ext_vector_type(16))) float f32x16;
typedef _Float16 f16x8 __attribute__((ext_vector_type(8)));
typedef unsigned int u32x4 __attribute__((ext_vector_type(4)));
typedef unsigned short u16x4 __attribute__((ext_vector_type(4)));

#define QMAXF 255.0f
#define MFMA_F16(a, b, c) __builtin_amdgcn_mfma_f32_32x32x16_f16(a, b, c, 0, 0, 0)

constexpr int Bb = 4, Ss = 1024, Ee = 1024, Hh = 16, Dd = 64;
constexpr int Mm = Bb * Ss;   // 4096
constexpr int F3 = 3 * Ee;    // 3072
constexpr int Kk = Ee;        // 1024

__device__ __forceinline__ unsigned short f2bf_exact(float f) {
    return (unsigned short)(__float_as_uint(f) >> 16);
}

// pack hi/lo f16 split of v into one u32: (lo16 << 16) | hi16   (RTE casts)
__device__ __forceinline__ unsigned pack_hl(float v) {
    _Float16 h = (_Float16)v;
    _Float16 l = (_Float16)(v - (float)h);
    return ((unsigned)__builtin_bit_cast(unsigned short, l) << 16) |
           (unsigned)__builtin_bit_cast(unsigned short, h);
}

// fused fake-quant of x, W_qkv, W_proj -> integer-valued bf16 (f32x4 vectorized)
__global__ void quant_all(const float* __restrict__ x,
                          const float* __restrict__ Wq,
                          const float* __restrict__ Wp,
                          const float* __restrict__ s_act, const float* __restrict__ zp_act,
                          const float* __restrict__ swq, const float* __restrict__ zwq,
                          const float* __restrict__ swp, const float* __restrict__ zwp,
                          unsigned short* __restrict__ xq,
                          unsigned short* __restrict__ wqq,
                          unsigned short* __restrict__ wpq) {
    constexpr int NX = Mm * Ee / 4;
    constexpr int NWQ = F3 * Ee / 4;
    constexpr int NWP = Ee * Ee / 4;
    const float sa = s_act[0], za = zp_act[0];
    for (int i = blockIdx.x * blockDim.x + threadIdx.x; i < NX + NWQ + NWP;
         i += gridDim.x * blockDim.x) {
        const float* src;
        unsigned short* dst;
        float s, zp;
        if (i < NX) {
            src = x + i * 4; dst = xq + i * 4; s = sa; zp = za;
        } else if (i < NX + NWQ) {
            int j = i - NX;
            int r = (j * 4) >> 10;
            src = Wq + j * 4; dst = wqq + j * 4; s = swq[r]; zp = zwq[r];
        } else {
            int j = i - NX - NWQ;
            int r = (j * 4) >> 10;
            src = Wp + j * 4; dst = wpq + j * 4; s = swp[r]; zp = zwp[r];
        }
        f32x4 v = *(const f32x4*)src;
        u16x4 o;
        #pragma unroll
        for (int e = 0; e < 4; ++e) {
            float q = v[e] / s + zp;
            q = fminf(fmaxf(q, 0.0f), QMAXF);
            o[e] = f2bf_exact(rintf(q) - zp);
        }
        *(u16x4*)dst = o;
    }
}

// bf16 integer MFMA GEMM (frozen numerics). BK=32 (R11-proven), BM=128 BN=64:
// smaller tiles -> 1536/512 blocks -> more resident waves per CU (TLP fix).
// Per-output MFMA chain order unchanged (kt ascending) -> bit-identical.
// MODE 0: q,k -> packed-hl u32 planes [BH][S][D]; v -> packed V^T [BH][D][S]
// MODE 1: fp32 [M][1024] to o0 (NT)
template<int MODE>
__global__ __launch_bounds__(256)
void gemm_fq(const unsigned short* __restrict__ A,
             const unsigned short* __restrict__ Bw,
             const float* __restrict__ sa_p,
             const float* __restrict__ sw_v,
             const float* __restrict__ bias_v,
             float* __restrict__ o0,
             unsigned* __restrict__ pq, unsigned* __restrict__ pk, unsigned* __restrict__ pv,
             int ntiles) {
    __shared__ unsigned short At[128][32];   // 8KB
    __shared__ unsigned short Bt[64][32];    // 4KB
    const int t = threadIdx.x;
    const int nwg = gridDim.x;
    const int swz = (blockIdx.x & 7) * (nwg >> 3) + (blockIdx.x >> 3);
    const int tile_m = (swz / ntiles) * 128;
    const int tile_n = (swz % ntiles) * 64;
    const int lane = t & 63, wid = t >> 6;
    const int wr = wid >> 1, wc = wid & 1;   // wave: rows wr*64..+64, cols wc*32..+32
    const int srow = t >> 1, scol = (t & 1) * 16;   // A staging
    const int brow = t >> 2, bcol = (t & 3) * 8;    // B staging
    const float sa = sa_p[0];

    const unsigned short* ga = A + (size_t)(tile_m + srow) * Kk + scol;
    const unsigned short* gb = Bw + (size_t)(tile_n + brow) * Kk + bcol;

    f32x4 acc[4][2];
    #pragma unroll
    for (int i = 0; i < 4; ++i)
        #pragma unroll
        for (int j = 0; j < 2; ++j)
            #pragma unroll
            for (int e = 0; e < 4; ++e) acc[i][j][e] = 0.0f;

    short8 ra0 = *(const short8*)(ga);
    short8 ra1 = *(const short8*)(ga + 8);
    short8 rb0 = *(const short8*)(gb);

    const int NKT = Kk / 32;
    for (int kt = 0; kt < NKT; ++kt) {
        __syncthreads();
        *(short8*)&At[srow][scol]     = ra0;
        *(short8*)&At[srow][scol + 8] = ra1;
        *(short8*)&Bt[brow][bcol]     = rb0;
        __syncthreads();
        // prefetch next K-slab into registers while MFMAs run
        int kn = (kt + 1 < NKT) ? (kt + 1) * 32 : kt * 32;
        ra0 = *(const short8*)(ga + kn);
        ra1 = *(const short8*)(ga + kn + 8);
        rb0 = *(const short8*)(gb + kn);

        const int kq = (lane >> 4) * 8;
        const int rowA = wr * 64 + (lane & 15);
        const int rowB = wc * 32 + (lane & 15);
        short8 af[4], bfr[2];
        #pragma unroll
        for (int i = 0; i < 4; ++i) af[i] = *(const short8*)&At[rowA + i * 16][kq];
        #pragma unroll
        for (int j = 0; j < 2; ++j) bfr[j] = *(const short8*)&Bt[rowB + j * 16][kq];
        __builtin_amdgcn_s_setprio(1);
        #pragma unroll
        for (int i = 0; i < 4; ++i)
            #pragma unroll
            for (int j = 0; j < 2; ++j)
                acc[i][j] = __builtin_amdgcn_mfma_f32_16x16x32_bf16(af[i], bfr[j], acc[i][j], 0, 0, 0);
        __builtin_amdgcn_s_setprio(0);
    }

    // C/D layout: col = lane&15, row = (lane>>4)*4 + reg
    const int lr4 = (lane >> 4) * 4;
    const int lc = lane & 15;
    #pragma unroll
    for (int j = 0; j < 2; ++j) {
        int n = tile_n + wc * 32 + j * 16 + lc;
        float sw = sw_v[n] * sa;
        float bv = bias_v[n];
        #pragma unroll
        for (int i = 0; i < 4; ++i) {
            int mbase = tile_m + wr * 64 + i * 16 + lr4;
            float vals[4];
            #pragma unroll
            for (int r = 0; r < 4; ++r) vals[r] = acc[i][j][r] * sw + bv;
            if (MODE == 0) {
                int which = n >> 10, hh = (n >> 6) & 15, d = n & 63;
                int bi = mbase >> 10, si0 = mbase & 1023;
                if (which == 2) {
                    u32x4 pv4;
                    #pragma unroll
                    for (int r = 0; r < 4; ++r) pv4[r] = pack_hl(vals[r]);
                    *(u32x4*)(pv + (((size_t)(bi * Hh + hh)) * Dd + d) * Ss + si0) = pv4;
                } else {
                    unsigned* dst = (which == 0) ? pq : pk;
                    #pragma unroll
                    for (int r = 0; r < 4; ++r)
                        dst[(((size_t)(bi * Hh + hh)) * Ss + si0 + r) * Dd + d] = pack_hl(vals[r]);
                }
            } else {
                #pragma unroll
                for (int r = 0; r < 4; ++r)
                    __builtin_nontemporal_store(vals[r], &o0[(size_t)(mbase + r) * Ee + n]);
            }
        }
    }
}

// Fused flash attention: packed-hl u32 inputs; v_perm unpack in staging
// reconstructs the SAME f16 hi/lo LDS image (bit-exact). XCD-grouped mapping.
__global__ __launch_bounds__(256, 2)
void attn_mfma(const unsigned* __restrict__ pq, const unsigned* __restrict__ pk,
               const unsigned* __restrict__ pv,
               const float* __restrict__ s_at_p, const float* __restrict__ zp_at_p,
               const float* __restrict__ s_ap_p, const float* __restrict__ zp_ap_p,
               unsigned short* __restrict__ outq) {
    __shared__ uint4 lds4[65536 / 16];   // 2 x 32KB double buffer
    char* lds = (char*)lds4;

    const int t = threadIdx.x;
    const int lane = t & 63;
    const int w = t >> 6;
    const int l31 = lane & 31;
    const int lhalf = lane >> 5;
    // XCD-grouped: xcd g&7 owns bh in [xcd*8, xcd*8+8); qt varies fastest
    const int g = blockIdx.x;
    const int ord = g >> 3;
    const int bh = (g & 7) * 8 + (ord >> 3);
    const int qt = ord & 7;
    const int b = bh >> 4, h = bh & 15;

    const float s_at = s_at_p[0], zp_at = zp_at_p[0];
    const float zp_ap = zp_ap_p[0];
    const float c1 = 0.125f / s_at;
    const float c2 = s_at * 1.44269504088896f;
    const float inv_sap = 1.0f / s_ap_p[0];

    #define UNPK_H(bx, ax) __builtin_amdgcn_perm((bx), (ax), 0x05040100u)
    #define UNPK_L(bx, ax) __builtin_amdgcn_perm((bx), (ax), 0x07060302u)

    // Q: load packed, unpack once
    const int qrow = qt * 128 + w * 32 + l31;
    const size_t qbase = ((size_t)bh * Ss + qrow) * Dd;
    f16x8 Qh[4], Ql[4];
    #pragma unroll
    for (int ks = 0; ks < 4; ++ks) {
        int dd = ks * 16 + lhalf * 8;
        u32x4 qa = *(const u32x4*)(pq + qbase + dd);
        u32x4 qb = *(const u32x4*)(pq + qbase + dd + 4);
        u32x4 hw, lw;
        hw[0] = UNPK_H(qa[1], qa[0]); lw[0] = UNPK_L(qa[1], qa[0]);
        hw[1] = UNPK_H(qa[3], qa[2]); lw[1] = UNPK_L(qa[3], qa[2]);
        hw[2] = UNPK_H(qb[1], qb[0]); lw[2] = UNPK_L(qb[1], qb[0]);
        hw[3] = UNPK_H(qb[3], qb[2]); lw[3] = UNPK_L(qb[3], qb[2]);
        Qh[ks] = __builtin_bit_cast(f16x8, hw);
        Ql[ks] = __builtin_bit_cast(f16x8, lw);
    }

    f32x16 o0, o1;
    #pragma unroll
    for (int i = 0; i < 16; ++i) { o0[i] = 0.0f; o1[i] = 0.0f; }
    float m_run = -1e30f, l_run = 0.0f;

    const int srow = t >> 2;              // 0..63
    const int sch = (t & 3) * 2;          // 0,2,4,6
    const int swz0 = ((sch    ) ^ (srow & 7)) << 4;
    const int swz1 = ((sch + 1) ^ (srow & 7)) << 4;
    const int rb = srow * 128;
    const size_t kgrow = ((size_t)bh * Ss + srow) * Dd + sch * 8;   // u32 elems
    const size_t vgrow = ((size_t)bh * Dd + srow) * Ss + sch * 8;

    u32x4 sk[4], sv[4];
    #define STAGE_LOAD(tl) {                                            \
        const size_t ko = kgrow + (size_t)(tl) * 64 * 64;               \
        const size_t vo = vgrow + (size_t)(tl) * 64;                    \
        sk[0] = *(const u32x4*)(pk + ko);                               \
        sk[1] = *(const u32x4*)(pk + ko + 4);                           \
        sk[2] = *(const u32x4*)(pk + ko + 8);                           \
        sk[3] = *(const u32x4*)(pk + ko + 12);                          \
        sv[0] = *(const u32x4*)(pv + vo);                               \
        sv[1] = *(const u32x4*)(pv + vo + 4);                           \
        sv[2] = *(const u32x4*)(pv + vo + 8);                           \
        sv[3] = *(const u32x4*)(pv + vo + 12);                          \
    }
    #define STAGE_WRITE(bsel) {                                         \
        u32x4 kh0, kl0, kh1, kl1, vh0, vl0, vh1, vl1;                   \
        _Pragma("unroll")                                               \
        for (int w2 = 0; w2 < 4; ++w2) {                                \
            unsigned a0 = sk[w2 >> 1][(w2 & 1) * 2];                    \
            unsigned b0 = sk[w2 >> 1][(w2 & 1) * 2 + 1];                \
            kh0[w2] = UNPK_H(b0, a0); kl0[w2] = UNPK_L(b0, a0);         \
            unsigned a1 = sk[2 + (w2 >> 1)][(w2 & 1) * 2];              \
            unsigned b1 = sk[2 + (w2 >> 1)][(w2 & 1) * 2 + 1];          \
            kh1[w2] = UNPK_H(b1, a1); kl1[w2] = UNPK_L(b1, a1);         \
            unsigned c0 = sv[w2 >> 1][(w2 & 1) * 2];                    \
            unsigned d0 = sv[w2 >> 1][(w2 & 1) * 2 + 1];                \
            vh0[w2] = UNPK_H(d0, c0); vl0[w2] = UNPK_L(d0, c0);         \
            unsigned c1x = sv[2 + (w2 >> 1)][(w2 & 1) * 2];             \
            unsigned d1 = sv[2 + (w2 >> 1)][(w2 & 1) * 2 + 1];          \
            vh1[w2] = UNPK_H(d1, c1x); vl1[w2] = UNPK_L(d1, c1x);       \
        }                                                               \
        char* base = lds + (bsel) * 32768;                              \
        *(u32x4*)(base +     0 + rb + swz0) = kh0;                      \
        *(u32x4*)(base +     0 + rb + swz1) = kh1;                      \
        *(u32x4*)(base +  8192 + rb + swz0) = kl0;                      \
        *(u32x4*)(base +  8192 + rb + swz1) = kl1;                      \
        *(u32x4*)(base + 16384 + rb + swz0) = vh0;                      \
        *(u32x4*)(base + 16384 + rb + swz1) = vh1;                      \
        *(u32x4*)(base + 24576 + rb + swz0) = vl0;                      \
        *(u32x4*)(base + 24576 + rb + swz1) = vl1;                      \
    }

    STAGE_LOAD(0);
    STAGE_WRITE(0);
    __syncthreads();

    for (int tile = 0; tile < 16; ++tile) {
        const int bsel = tile & 1;
        char* B = lds + bsel * 32768;
        if (tile < 15) STAGE_LOAD(tile + 1);

        // ---- S^T = K * Q^T (3 split products) ----
        f32x16 s0, s1;
        #pragma unroll
        for (int i = 0; i < 16; ++i) { s0[i] = 0.0f; s1[i] = 0.0f; }
        __builtin_amdgcn_s_setprio(1);
        #pragma unroll
        for (int ks = 0; ks < 4; ++ks) {
            const int dchunk = ks * 2 + lhalf;
            {
                const int kr = l31;
                const char* a = B + kr * 128 + ((dchunk ^ (kr & 7)) << 4);
                f16x8 ah = *(const f16x8*)(a);
                f16x8 al = *(const f16x8*)(a + 8192);
                s0 = MFMA_F16(ah, Qh[ks], s0);
                s0 = MFMA_F16(ah, Ql[ks], s0);
                s0 = MFMA_F16(al, Qh[ks], s0);
            }
            {
                const int kr = 32 + l31;
                const char* a = B + kr * 128 + ((dchunk ^ (kr & 7)) << 4);
                f16x8 ah = *(const f16x8*)(a);
                f16x8 al = *(const f16x8*)(a + 8192);
                s1 = MFMA_F16(ah, Qh[ks], s1);
                s1 = MFMA_F16(ah, Ql[ks], s1);
                s1 = MFMA_F16(al, Qh[ks], s1);
            }
        }
        __builtin_amdgcn_s_setprio(0);

        // ---- integer-domain fake-quant + online softmax ----
        float rq[32];
        #pragma unroll
        for (int r = 0; r < 16; ++r) {
            float q0 = fmaf(s0[r], c1, zp_at);
            q0 = fminf(fmaxf(q0, 0.0f), QMAXF);
            rq[r] = rintf(q0);
            float q1 = fmaf(s1[r], c1, zp_at);
            q1 = fminf(fmaxf(q1, 0.0f), QMAXF);
            rq[16 + r] = rintf(q1);
        }
        float mx[16];
        #pragma unroll
        for (int i = 0; i < 16; ++i) mx[i] = fmaxf(rq[2 * i], rq[2 * i + 1]);
        #pragma unroll
        for (int i = 0; i < 8; ++i) mx[i] = fmaxf(mx[i], mx[i + 8]);
        #pragma unroll
        for (int i = 0; i < 4; ++i) mx[i] = fmaxf(mx[i], mx[i + 4]);
        float mloc = fmaxf(fmaxf(mx[0], mx[1]), fmaxf(mx[2], mx[3]));
        mloc = fmaxf(mloc, __shfl_xor(mloc, 32));

        if (!__all(mloc - m_run <= 64.0f)) {   // defer-max: rare rescale
            float mnew = fmaxf(m_run, mloc);
            float fac = exp2f((m_run - mnew) * c2);
            l_run *= fac;
            #pragma unroll
            for (int r = 0; r < 16; ++r) {
                int qr = (r & 3) + 8 * (r >> 2) + 4 * lhalf;
                float f = __shfl(fac, qr);
                o0[r] *= f; o1[r] *= f;
            }
            m_run = mnew;
        }

        float p[32];
        float psum = 0.0f;
        #pragma unroll
        for (int i = 0; i < 32; ++i) {
            p[i] = exp2f((rq[i] - m_run) * c2);
            psum += p[i];
        }
        psum += __shfl_xor(psum, 32);
        l_run += psum;

        // ---- pack P hi/lo + permlane32_swap into A-fragments ----
        unsigned int wH[16], wL[16];
        #pragma unroll
        for (int wi = 0; wi < 16; ++wi) {
            float a = p[2 * wi], bb2 = p[2 * wi + 1];
            auto hh2 = __builtin_amdgcn_cvt_pkrtz(a, bb2);
            wH[wi] = __builtin_bit_cast(unsigned int, hh2);
            float ha = (float)hh2[0], hb = (float)hh2[1];
            auto ll2 = __builtin_amdgcn_cvt_pkrtz(a - ha, bb2 - hb);
            wL[wi] = __builtin_bit_cast(unsigned int, ll2);
        }
        f16x8 fragH[4], fragL[4];
        #pragma unroll
        for (int ks = 0; ks < 4; ++ks) {
            auto h0 = __builtin_amdgcn_permlane32_swap(wH[4 * ks], wH[4 * ks + 2], false, false);
            auto h1 = __builtin_amdgcn_permlane32_swap(wH[4 * ks + 1], wH[4 * ks + 3], false, false);
            fragH[ks] = __builtin_bit_cast(f16x8, (u32x4){h0[0], h1[0], h0[1], h1[1]});
            auto g0 = __builtin_amdgcn_permlane32_swap(wL[4 * ks], wL[4 * ks + 2], false, false);
            auto g1 = __builtin_amdgcn_permlane32_swap(wL[4 * ks + 1], wL[4 * ks + 3], false, false);
            fragL[ks] = __builtin_bit_cast(f16x8, (u32x4){g0[0], g1[0], g0[1], g1[1]});
        }

        // ---- O += P * V (3 split products) ----
        __builtin_amdgcn_s_setprio(1);
        #pragma unroll
        for (int ks = 0; ks < 4; ++ks) {
            const int kch = ks * 2 + lhalf;
            {
                const int dd = l31;
                const char* va = B + 16384 + dd * 128 + ((kch ^ (dd & 7)) << 4);
                f16x8 vh = *(const f16x8*)(va);
                f16x8 vl = *(const f16x8*)(va + 8192);
                o0 = MFMA_F16(fragH[ks], vh, o0);
                o0 = MFMA_F16(fragH[ks], vl, o0);
                o0 = MFMA_F16(fragL[ks], vh, o0);
            }
            {
                const int dd = 32 + l31;
                const char* va = B + 16384 + dd * 128 + ((kch ^ (dd & 7)) << 4);
                f16x8 vh = *(const f16x8*)(va);
                f16x8 vl = *(const f16x8*)(va + 8192);
                o1 = MFMA_F16(fragH[ks], vh, o1);
                o1 = MFMA_F16(fragH[ks], vl, o1);
                o1 = MFMA_F16(fragL[ks], vh, o1);
            }
        }
        __builtin_amdgcn_s_setprio(0);

        if (tile < 15) STAGE_WRITE(bsel ^ 1);
        __syncthreads();
    }

    // ---- epilogue: /l, proj-activation fake-quant, write bf16-int (NT) ----
    float inv = 1.0f / l_run;
    #pragma unroll
    for (int r = 0; r < 16; ++r) {
        int qr = (r & 3) + 8 * (r >> 2) + 4 * lhalf;
        float fis = __shfl(inv, qr) * inv_sap;
        int tok = qt * 128 + w * 32 + qr;
        size_t rowbase = ((size_t)b * Ss + tok) * Ee + h * Dd;
        {
            float qv = fmaf(o0[r], fis, zp_ap);
            qv = fminf(fmaxf(qv, 0.0f), QMAXF);
            __builtin_nontemporal_store(f2bf_exact(rintf(qv) - zp_ap), &outq[rowbase + l31]);
        }
        {
            float qv = fmaf(o1[r], fis, zp_ap);
            qv = fminf(fmaxf(qv, 0.0f), QMAXF);
            __builtin_nontemporal_store(f2bf_exact(rintf(qv) - zp_ap), &outq[rowbase + 32 + l31]);
        }
    }
}

extern "C" void kernel_launch(void* const* d_in, const int* in_sizes, int n_in,
                              void* d_out, int out_size, void* d_ws, size_t ws_size,
                              hipStream_t stream) {
    const float* x           = (const float*)d_in[0];
    const float* W_qkv       = (const float*)d_in[1];
    const float* b_qkv       = (const float*)d_in[2];
    const float* W_proj      = (const float*)d_in[3];
    const float* b_proj      = (const float*)d_in[4];
    const float* s_act_qkv   = (const float*)d_in[5];
    const float* zp_act_qkv  = (const float*)d_in[6];
    const float* s_w_qkv     = (const float*)d_in[7];
    const float* zp_w_qkv    = (const float*)d_in[8];
    const float* s_attn      = (const float*)d_in[9];
    const float* zp_attn     = (const float*)d_in[10];
    const float* s_act_proj  = (const float*)d_in[11];
    const float* zp_act_proj = (const float*)d_in[12];
    const float* s_w_proj    = (const float*)d_in[13];
    const float* zp_w_proj   = (const float*)d_in[14];

    // ws layout (64MB): 0 xq/outq(8) | 8 wqq(6) | 14 wpq(2) | 16 pq(16) | 32 pk(16) | 48 pv(16)
    char* ws = (char*)d_ws;
    unsigned short* xq   = (unsigned short*)(ws);
    unsigned short* outq = (unsigned short*)(ws);
    unsigned short* wqq  = (unsigned short*)(ws + ((size_t)8 << 20));
    unsigned short* wpq  = (unsigned short*)(ws + ((size_t)14 << 20));
    unsigned* pq         = (unsigned*)(ws + ((size_t)16 << 20));
    unsigned* pk         = (unsigned*)(ws + ((size_t)32 << 20));
    unsigned* pv         = (unsigned*)(ws + ((size_t)48 << 20));

    quant_all<<<2048, 256, 0, stream>>>(x, W_qkv, W_proj,
                                        s_act_qkv, zp_act_qkv, s_w_qkv, zp_w_qkv,
                                        s_w_proj, zp_w_proj, xq, wqq, wpq);
    gemm_fq<0><<<1536, 256, 0, stream>>>(xq, wqq, s_act_qkv, s_w_qkv, b_qkv,
                                         nullptr, pq, pk, pv, 48);
    attn_mfma<<<512, 256, 0, stream>>>(pq, pk, pv,
                                       s_attn, zp_attn, s_act_proj, zp_act_proj, outq);
    gemm_fq<1><<<512, 256, 0, stream>>>(outq, wpq, s_act_proj, s_w_proj, b_proj,
                                        (float*)d_out, nullptr, nullptr, nullptr, 16);
}

// Round 14
// 140.668 us; speedup vs baseline: 1.1284x; 1.0959x over previous
//
#include <hip/hip_runtime.h>
#include <hip/hip_bf16.h>
#include <stdint.h>

typedef __attribute__((ext_vector_type(8))) short short8;
typedef __attribute__((ext_vector_type(4))) float f32x4;
typedef __attribute__((ext_vector_type(16))) float f32x16;
typedef _Float16 f16x8 __attribute__((ext_vector_type(8)));
typedef unsigned int u32x4 __attribute__((ext_vector_type(4)));
typedef unsigned short u16x4 __attribute__((ext_vector_type(4)));

#define QMAXF 255.0f
#define MFMA_F16(a, b, c) __builtin_amdgcn_mfma_f32_32x32x16_f16(a, b, c, 0, 0, 0)

constexpr int Bb = 4, Ss = 1024, Ee = 1024, Hh = 16, Dd = 64;
constexpr int Mm = Bb * Ss;   // 4096
constexpr int F3 = 3 * Ee;    // 3072
constexpr int Kk = Ee;        // 1024

__device__ __forceinline__ unsigned short f2bf_exact(float f) {
    return (unsigned short)(__float_as_uint(f) >> 16);
}

// pack hi/lo f16 split of v into one u32: (lo16 << 16) | hi16   (RTE casts)
__device__ __forceinline__ unsigned pack_hl(float v) {
    _Float16 h = (_Float16)v;
    _Float16 l = (_Float16)(v - (float)h);
    return ((unsigned)__builtin_bit_cast(unsigned short, l) << 16) |
           (unsigned)__builtin_bit_cast(unsigned short, h);
}

// fused fake-quant of x, W_qkv, W_proj -> integer-valued bf16 (f32x4 vectorized)
__global__ void quant_all(const float* __restrict__ x,
                          const float* __restrict__ Wq,
                          const float* __restrict__ Wp,
                          const float* __restrict__ s_act, const float* __restrict__ zp_act,
                          const float* __restrict__ swq, const float* __restrict__ zwq,
                          const float* __restrict__ swp, const float* __restrict__ zwp,
                          unsigned short* __restrict__ xq,
                          unsigned short* __restrict__ wqq,
                          unsigned short* __restrict__ wpq) {
    constexpr int NX = Mm * Ee / 4;
    constexpr int NWQ = F3 * Ee / 4;
    constexpr int NWP = Ee * Ee / 4;
    const float sa = s_act[0], za = zp_act[0];
    for (int i = blockIdx.x * blockDim.x + threadIdx.x; i < NX + NWQ + NWP;
         i += gridDim.x * blockDim.x) {
        const float* src;
        unsigned short* dst;
        float s, zp;
        if (i < NX) {
            src = x + i * 4; dst = xq + i * 4; s = sa; zp = za;
        } else if (i < NX + NWQ) {
            int j = i - NX;
            int r = (j * 4) >> 10;
            src = Wq + j * 4; dst = wqq + j * 4; s = swq[r]; zp = zwq[r];
        } else {
            int j = i - NX - NWQ;
            int r = (j * 4) >> 10;
            src = Wp + j * 4; dst = wpq + j * 4; s = swp[r]; zp = zwp[r];
        }
        f32x4 v = *(const f32x4*)src;
        u16x4 o;
        #pragma unroll
        for (int e = 0; e < 4; ++e) {
            float q = v[e] / s + zp;
            q = fminf(fmaxf(q, 0.0f), QMAXF);
            o[e] = f2bf_exact(rintf(q) - zp);
        }
        *(u16x4*)dst = o;
    }
}

// bf16 integer MFMA GEMM (frozen numerics). BK=32, 128x128 tile, reg-staged
// (R11-proven best across 7 structural variants).
// MODE 0: q,k -> packed-hl u32 planes [BH][S][D]; v -> packed V^T [BH][D][S]
// MODE 1: fp32 [M][1024] to o0 (NT)
template<int MODE>
__global__ __launch_bounds__(256)
void gemm_fq(const unsigned short* __restrict__ A,
             const unsigned short* __restrict__ Bw,
             const float* __restrict__ sa_p,
             const float* __restrict__ sw_v,
             const float* __restrict__ bias_v,
             float* __restrict__ o0,
             unsigned* __restrict__ pq, unsigned* __restrict__ pk, unsigned* __restrict__ pv,
             int ntiles) {
    __shared__ unsigned short At[128][32];
    __shared__ unsigned short Bt[128][32];
    const int t = threadIdx.x;
    const int nwg = gridDim.x;
    const int swz = (blockIdx.x & 7) * (nwg >> 3) + (blockIdx.x >> 3);
    const int tile_m = (swz / ntiles) * 128;
    const int tile_n = (swz % ntiles) * 128;
    const int lane = t & 63, wid = t >> 6;
    const int wr = wid >> 1, wc = wid & 1;
    const int srow = t >> 1, scol = (t & 1) * 16;
    const float sa = sa_p[0];

    const unsigned short* ga = A + (size_t)(tile_m + srow) * Kk + scol;
    const unsigned short* gb = Bw + (size_t)(tile_n + srow) * Kk + scol;

    f32x4 acc[4][4];
    #pragma unroll
    for (int i = 0; i < 4; ++i)
        #pragma unroll
        for (int j = 0; j < 4; ++j)
            #pragma unroll
            for (int e = 0; e < 4; ++e) acc[i][j][e] = 0.0f;

    short8 ra0 = *(const short8*)(ga);
    short8 ra1 = *(const short8*)(ga + 8);
    short8 rb0 = *(const short8*)(gb);
    short8 rb1 = *(const short8*)(gb + 8);

    const int NKT = Kk / 32;
    for (int kt = 0; kt < NKT; ++kt) {
        __syncthreads();
        *(short8*)&At[srow][scol]     = ra0;
        *(short8*)&At[srow][scol + 8] = ra1;
        *(short8*)&Bt[srow][scol]     = rb0;
        *(short8*)&Bt[srow][scol + 8] = rb1;
        __syncthreads();
        int kn = (kt + 1 < NKT) ? (kt + 1) * 32 : kt * 32;
        ra0 = *(const short8*)(ga + kn);
        ra1 = *(const short8*)(ga + kn + 8);
        rb0 = *(const short8*)(gb + kn);
        rb1 = *(const short8*)(gb + kn + 8);

        const int kq = (lane >> 4) * 8;
        const int rowA = wr * 64 + (lane & 15);
        const int rowB = wc * 64 + (lane & 15);
        short8 af[4], bfr[4];
        #pragma unroll
        for (int i = 0; i < 4; ++i) af[i] = *(const short8*)&At[rowA + i * 16][kq];
        #pragma unroll
        for (int j = 0; j < 4; ++j) bfr[j] = *(const short8*)&Bt[rowB + j * 16][kq];
        __builtin_amdgcn_s_setprio(1);
        #pragma unroll
        for (int i = 0; i < 4; ++i)
            #pragma unroll
            for (int j = 0; j < 4; ++j)
                acc[i][j] = __builtin_amdgcn_mfma_f32_16x16x32_bf16(af[i], bfr[j], acc[i][j], 0, 0, 0);
        __builtin_amdgcn_s_setprio(0);
    }

    // C/D layout: col = lane&15, row = (lane>>4)*4 + reg
    const int lr4 = (lane >> 4) * 4;
    const int lc = lane & 15;
    #pragma unroll
    for (int j = 0; j < 4; ++j) {
        int n = tile_n + wc * 64 + j * 16 + lc;
        float sw = sw_v[n] * sa;
        float bv = bias_v[n];
        #pragma unroll
        for (int i = 0; i < 4; ++i) {
            int mbase = tile_m + wr * 64 + i * 16 + lr4;
            float vals[4];
            #pragma unroll
            for (int r = 0; r < 4; ++r) vals[r] = acc[i][j][r] * sw + bv;
            if (MODE == 0) {
                int which = n >> 10, hh = (n >> 6) & 15, d = n & 63;
                int bi = mbase >> 10, si0 = mbase & 1023;
                if (which == 2) {
                    u32x4 pv4;
                    #pragma unroll
                    for (int r = 0; r < 4; ++r) pv4[r] = pack_hl(vals[r]);
                    *(u32x4*)(pv + (((size_t)(bi * Hh + hh)) * Dd + d) * Ss + si0) = pv4;
                } else {
                    unsigned* dst = (which == 0) ? pq : pk;
                    #pragma unroll
                    for (int r = 0; r < 4; ++r)
                        dst[(((size_t)(bi * Hh + hh)) * Ss + si0 + r) * Dd + d] = pack_hl(vals[r]);
                }
            } else {
                #pragma unroll
                for (int r = 0; r < 4; ++r)
                    __builtin_nontemporal_store(vals[r], &o0[(size_t)(mbase + r) * Ee + n]);
            }
        }
    }
}

// Fused flash attention: packed-hl u32 inputs; v_perm unpack in staging
// reconstructs the SAME f16 hi/lo LDS image (bit-exact). XCD-grouped mapping.
__global__ __launch_bounds__(256, 2)
void attn_mfma(const unsigned* __restrict__ pq, const unsigned* __restrict__ pk,
               const unsigned* __restrict__ pv,
               const float* __restrict__ s_at_p, const float* __restrict__ zp_at_p,
               const float* __restrict__ s_ap_p, const float* __restrict__ zp_ap_p,
               unsigned short* __restrict__ outq) {
    __shared__ uint4 lds4[65536 / 16];   // 2 x 32KB double buffer
    char* lds = (char*)lds4;

    const int t = threadIdx.x;
    const int lane = t & 63;
    const int w = t >> 6;
    const int l31 = lane & 31;
    const int lhalf = lane >> 5;
    // XCD-grouped: xcd g&7 owns bh in [xcd*8, xcd*8+8); qt varies fastest
    const int g = blockIdx.x;
    const int ord = g >> 3;
    const int bh = (g & 7) * 8 + (ord >> 3);
    const int qt = ord & 7;
    const int b = bh >> 4, h = bh & 15;

    const float s_at = s_at_p[0], zp_at = zp_at_p[0];
    const float zp_ap = zp_ap_p[0];
    const float c1 = 0.125f / s_at;
    const float c2 = s_at * 1.44269504088896f;
    const float inv_sap = 1.0f / s_ap_p[0];

    #define UNPK_H(bx, ax) __builtin_amdgcn_perm((bx), (ax), 0x05040100u)
    #define UNPK_L(bx, ax) __builtin_amdgcn_perm((bx), (ax), 0x07060302u)

    // Q: load packed, unpack once
    const int qrow = qt * 128 + w * 32 + l31;
    const size_t qbase = ((size_t)bh * Ss + qrow) * Dd;
    f16x8 Qh[4], Ql[4];
    #pragma unroll
    for (int ks = 0; ks < 4; ++ks) {
        int dd = ks * 16 + lhalf * 8;
        u32x4 qa = *(const u32x4*)(pq + qbase + dd);
        u32x4 qb = *(const u32x4*)(pq + qbase + dd + 4);
        u32x4 hw, lw;
        hw[0] = UNPK_H(qa[1], qa[0]); lw[0] = UNPK_L(qa[1], qa[0]);
        hw[1] = UNPK_H(qa[3], qa[2]); lw[1] = UNPK_L(qa[3], qa[2]);
        hw[2] = UNPK_H(qb[1], qb[0]); lw[2] = UNPK_L(qb[1], qb[0]);
        hw[3] = UNPK_H(qb[3], qb[2]); lw[3] = UNPK_L(qb[3], qb[2]);
        Qh[ks] = __builtin_bit_cast(f16x8, hw);
        Ql[ks] = __builtin_bit_cast(f16x8, lw);
    }

    f32x16 o0, o1;
    #pragma unroll
    for (int i = 0; i < 16; ++i) { o0[i] = 0.0f; o1[i] = 0.0f; }
    float m_run = -1e30f, l_run = 0.0f;

    const int srow = t >> 2;              // 0..63
    const int sch = (t & 3) * 2;          // 0,2,4,6
    const int swz0 = ((sch    ) ^ (srow & 7)) << 4;
    const int swz1 = ((sch + 1) ^ (srow & 7)) << 4;
    const int rb = srow * 128;
    const size_t kgrow = ((size_t)bh * Ss + srow) * Dd + sch * 8;   // u32 elems
    const size_t vgrow = ((size_t)bh * Dd + srow) * Ss + sch * 8;

    u32x4 sk[4], sv[4];
    #define STAGE_LOAD(tl) {                                            \
        const size_t ko = kgrow + (size_t)(tl) * 64 * 64;               \
        const size_t vo = vgrow + (size_t)(tl) * 64;                    \
        sk[0] = *(const u32x4*)(pk + ko);                               \
        sk[1] = *(const u32x4*)(pk + ko + 4);                           \
        sk[2] = *(const u32x4*)(pk + ko + 8);                           \
        sk[3] = *(const u32x4*)(pk + ko + 12);                          \
        sv[0] = *(const u32x4*)(pv + vo);                               \
        sv[1] = *(const u32x4*)(pv + vo + 4);                           \
        sv[2] = *(const u32x4*)(pv + vo + 8);                           \
        sv[3] = *(const u32x4*)(pv + vo + 12);                          \
    }
    #define STAGE_WRITE(bsel) {                                         \
        u32x4 kh0, kl0, kh1, kl1, vh0, vl0, vh1, vl1;                   \
        _Pragma("unroll")                                               \
        for (int w2 = 0; w2 < 4; ++w2) {                                \
            unsigned a0 = sk[w2 >> 1][(w2 & 1) * 2];                    \
            unsigned b0 = sk[w2 >> 1][(w2 & 1) * 2 + 1];                \
            kh0[w2] = UNPK_H(b0, a0); kl0[w2] = UNPK_L(b0, a0);         \
            unsigned a1 = sk[2 + (w2 >> 1)][(w2 & 1) * 2];              \
            unsigned b1 = sk[2 + (w2 >> 1)][(w2 & 1) * 2 + 1];          \
            kh1[w2] = UNPK_H(b1, a1); kl1[w2] = UNPK_L(b1, a1);         \
            unsigned c0 = sv[w2 >> 1][(w2 & 1) * 2];                    \
            unsigned d0 = sv[w2 >> 1][(w2 & 1) * 2 + 1];                \
            vh0[w2] = UNPK_H(d0, c0); vl0[w2] = UNPK_L(d0, c0);         \
            unsigned c1x = sv[2 + (w2 >> 1)][(w2 & 1) * 2];             \
            unsigned d1 = sv[2 + (w2 >> 1)][(w2 & 1) * 2 + 1];          \
            vh1[w2] = UNPK_H(d1, c1x); vl1[w2] = UNPK_L(d1, c1x);       \
        }                                                               \
        char* base = lds + (bsel) * 32768;                              \
        *(u32x4*)(base +     0 + rb + swz0) = kh0;                      \
        *(u32x4*)(base +     0 + rb + swz1) = kh1;                      \
        *(u32x4*)(base +  8192 + rb + swz0) = kl0;                      \
        *(u32x4*)(base +  8192 + rb + swz1) = kl1;                      \
        *(u32x4*)(base + 16384 + rb + swz0) = vh0;                      \
        *(u32x4*)(base + 16384 + rb + swz1) = vh1;                      \
        *(u32x4*)(base + 24576 + rb + swz0) = vl0;                      \
        *(u32x4*)(base + 24576 + rb + swz1) = vl1;                      \
    }

    STAGE_LOAD(0);
    STAGE_WRITE(0);
    __syncthreads();

    for (int tile = 0; tile < 16; ++tile) {
        const int bsel = tile & 1;
        char* B = lds + bsel * 32768;
        if (tile < 15) STAGE_LOAD(tile + 1);

        // ---- S^T = K * Q^T (3 split products) ----
        f32x16 s0, s1;
        #pragma unroll
        for (int i = 0; i < 16; ++i) { s0[i] = 0.0f; s1[i] = 0.0f; }
        __builtin_amdgcn_s_setprio(1);
        #pragma unroll
        for (int ks = 0; ks < 4; ++ks) {
            const int dchunk = ks * 2 + lhalf;
            {
                const int kr = l31;
                const char* a = B + kr * 128 + ((dchunk ^ (kr & 7)) << 4);
                f16x8 ah = *(const f16x8*)(a);
                f16x8 al = *(const f16x8*)(a + 8192);
                s0 = MFMA_F16(ah, Qh[ks], s0);
                s0 = MFMA_F16(ah, Ql[ks], s0);
                s0 = MFMA_F16(al, Qh[ks], s0);
            }
            {
                const int kr = 32 + l31;
                const char* a = B + kr * 128 + ((dchunk ^ (kr & 7)) << 4);
                f16x8 ah = *(const f16x8*)(a);
                f16x8 al = *(const f16x8*)(a + 8192);
                s1 = MFMA_F16(ah, Qh[ks], s1);
                s1 = MFMA_F16(ah, Ql[ks], s1);
                s1 = MFMA_F16(al, Qh[ks], s1);
            }
        }
        __builtin_amdgcn_s_setprio(0);

        // ---- integer-domain fake-quant + online softmax ----
        float rq[32];
        #pragma unroll
        for (int r = 0; r < 16; ++r) {
            float q0 = fmaf(s0[r], c1, zp_at);
            q0 = fminf(fmaxf(q0, 0.0f), QMAXF);
            rq[r] = rintf(q0);
            float q1 = fmaf(s1[r], c1, zp_at);
            q1 = fminf(fmaxf(q1, 0.0f), QMAXF);
            rq[16 + r] = rintf(q1);
        }
        float mx[16];
        #pragma unroll
        for (int i = 0; i < 16; ++i) mx[i] = fmaxf(rq[2 * i], rq[2 * i + 1]);
        #pragma unroll
        for (int i = 0; i < 8; ++i) mx[i] = fmaxf(mx[i], mx[i + 8]);
        #pragma unroll
        for (int i = 0; i < 4; ++i) mx[i] = fmaxf(mx[i], mx[i + 4]);
        float mloc = fmaxf(fmaxf(mx[0], mx[1]), fmaxf(mx[2], mx[3]));
        mloc = fmaxf(mloc, __shfl_xor(mloc, 32));

        if (!__all(mloc - m_run <= 64.0f)) {   // defer-max: rare rescale
            float mnew = fmaxf(m_run, mloc);
            float fac = exp2f((m_run - mnew) * c2);
            l_run *= fac;
            #pragma unroll
            for (int r = 0; r < 16; ++r) {
                int qr = (r & 3) + 8 * (r >> 2) + 4 * lhalf;
                float f = __shfl(fac, qr);
                o0[r] *= f; o1[r] *= f;
            }
            m_run = mnew;
        }

        float p[32];
        float psum = 0.0f;
        #pragma unroll
        for (int i = 0; i < 32; ++i) {
            p[i] = exp2f((rq[i] - m_run) * c2);
            psum += p[i];
        }
        psum += __shfl_xor(psum, 32);
        l_run += psum;

        // ---- pack P hi/lo + permlane32_swap into A-fragments ----
        unsigned int wH[16], wL[16];
        #pragma unroll
        for (int wi = 0; wi < 16; ++wi) {
            float a = p[2 * wi], bb2 = p[2 * wi + 1];
            auto hh2 = __builtin_amdgcn_cvt_pkrtz(a, bb2);
            wH[wi] = __builtin_bit_cast(unsigned int, hh2);
            float ha = (float)hh2[0], hb = (float)hh2[1];
            auto ll2 = __builtin_amdgcn_cvt_pkrtz(a - ha, bb2 - hb);
            wL[wi] = __builtin_bit_cast(unsigned int, ll2);
        }
        f16x8 fragH[4], fragL[4];
        #pragma unroll
        for (int ks = 0; ks < 4; ++ks) {
            auto h0 = __builtin_amdgcn_permlane32_swap(wH[4 * ks], wH[4 * ks + 2], false, false);
            auto h1 = __builtin_amdgcn_permlane32_swap(wH[4 * ks + 1], wH[4 * ks + 3], false, false);
            fragH[ks] = __builtin_bit_cast(f16x8, (u32x4){h0[0], h1[0], h0[1], h1[1]});
            auto g0 = __builtin_amdgcn_permlane32_swap(wL[4 * ks], wL[4 * ks + 2], false, false);
            auto g1 = __builtin_amdgcn_permlane32_swap(wL[4 * ks + 1], wL[4 * ks + 3], false, false);
            fragL[ks] = __builtin_bit_cast(f16x8, (u32x4){g0[0], g1[0], g0[1], g1[1]});
        }

        // ---- O += P * V (3 split products) ----
        __builtin_amdgcn_s_setprio(1);
        #pragma unroll
        for (int ks = 0; ks < 4; ++ks) {
            const int kch = ks * 2 + lhalf;
            {
                const int dd = l31;
                const char* va = B + 16384 + dd * 128 + ((kch ^ (dd & 7)) << 4);
                f16x8 vh = *(const f16x8*)(va);
                f16x8 vl = *(const f16x8*)(va + 8192);
                o0 = MFMA_F16(fragH[ks], vh, o0);
                o0 = MFMA_F16(fragH[ks], vl, o0);
                o0 = MFMA_F16(fragL[ks], vh, o0);
            }
            {
                const int dd = 32 + l31;
                const char* va = B + 16384 + dd * 128 + ((kch ^ (dd & 7)) << 4);
                f16x8 vh = *(const f16x8*)(va);
                f16x8 vl = *(const f16x8*)(va + 8192);
                o1 = MFMA_F16(fragH[ks], vh, o1);
                o1 = MFMA_F16(fragH[ks], vl, o1);
                o1 = MFMA_F16(fragL[ks], vh, o1);
            }
        }
        __builtin_amdgcn_s_setprio(0);

        if (tile < 15) STAGE_WRITE(bsel ^ 1);
        __syncthreads();
    }

    // ---- epilogue: /l, proj-activation fake-quant, write bf16-int (NT) ----
    float inv = 1.0f / l_run;
    #pragma unroll
    for (int r = 0; r < 16; ++r) {
        int qr = (r & 3) + 8 * (r >> 2) + 4 * lhalf;
        float fis = __shfl(inv, qr) * inv_sap;
        int tok = qt * 128 + w * 32 + qr;
        size_t rowbase = ((size_t)b * Ss + tok) * Ee + h * Dd;
        {
            float qv = fmaf(o0[r], fis, zp_ap);
            qv = fminf(fmaxf(qv, 0.0f), QMAXF);
            __builtin_nontemporal_store(f2bf_exact(rintf(qv) - zp_ap), &outq[rowbase + l31]);
        }
        {
            float qv = fmaf(o1[r], fis, zp_ap);
            qv = fminf(fmaxf(qv, 0.0f), QMAXF);
            __builtin_nontemporal_store(f2bf_exact(rintf(qv) - zp_ap), &outq[rowbase + 32 + l31]);
        }
    }
}

extern "C" void kernel_launch(void* const* d_in, const int* in_sizes, int n_in,
                              void* d_out, int out_size, void* d_ws, size_t ws_size,
                              hipStream_t stream) {
    const float* x           = (const float*)d_in[0];
    const float* W_qkv       = (const float*)d_in[1];
    const float* b_qkv       = (const float*)d_in[2];
    const float* W_proj      = (const float*)d_in[3];
    const float* b_proj      = (const float*)d_in[4];
    const float* s_act_qkv   = (const float*)d_in[5];
    const float* zp_act_qkv  = (const float*)d_in[6];
    const float* s_w_qkv     = (const float*)d_in[7];
    const float* zp_w_qkv    = (const float*)d_in[8];
    const float* s_attn      = (const float*)d_in[9];
    const float* zp_attn     = (const float*)d_in[10];
    const float* s_act_proj  = (const float*)d_in[11];
    const float* zp_act_proj = (const float*)d_in[12];
    const float* s_w_proj    = (const float*)d_in[13];
    const float* zp_w_proj   = (const float*)d_in[14];

    // ws layout (64MB): 0 xq/outq(8) | 8 wqq(6) | 14 wpq(2) | 16 pq(16) | 32 pk(16) | 48 pv(16)
    char* ws = (char*)d_ws;
    unsigned short* xq   = (unsigned short*)(ws);
    unsigned short* outq = (unsigned short*)(ws);
    unsigned short* wqq  = (unsigned short*)(ws + ((size_t)8 << 20));
    unsigned short* wpq  = (unsigned short*)(ws + ((size_t)14 << 20));
    unsigned* pq         = (unsigned*)(ws + ((size_t)16 << 20));
    unsigned* pk         = (unsigned*)(ws + ((size_t)32 << 20));
    unsigned* pv         = (unsigned*)(ws + ((size_t)48 << 20));

    quant_all<<<2048, 256, 0, stream>>>(x, W_qkv, W_proj,
                                        s_act_qkv, zp_act_qkv, s_w_qkv, zp_w_qkv,
                                        s_w_proj, zp_w_proj, xq, wqq, wpq);
    gemm_fq<0><<<768, 256, 0, stream>>>(xq, wqq, s_act_qkv, s_w_qkv, b_qkv,
                                        nullptr, pq, pk, pv, 24);
    attn_mfma<<<512, 256, 0, stream>>>(pq, pk, pv,
                                       s_attn, zp_attn, s_act_proj, zp_act_proj, outq);
    gemm_fq<1><<<256, 256, 0, stream>>>(outq, wpq, s_act_proj, s_w_proj, b_proj,
                                        (float*)d_out, nullptr, nullptr, nullptr, 8);
}